// Round 2
// baseline (542.333 us; speedup 1.0000x reference)
//
#include <hip/hip_runtime.h>

// SGNS scoring: out[b] = dot(W[vii[b,0]], W[vii[b,1]]) over 128 fp32 dims.
// W: fp32 [1e6 x 128] (rows = 512 B), vii: int64 or int32 [16384 x 2]
// (width auto-detected), out: fp32 [16384].
// Latency-bound random gather: 16 lanes/sample, 2x float4 per lane per row
// -> each 512 B row read as 32 contiguous float4s (8 full cachelines).

#define BATCH 16384
#define NB_DIMS 128
#define LPS 16                      // lanes per sample
#define BLOCK 256
#define SPB (BLOCK / LPS)           // 16 samples per block

__global__ __launch_bounds__(BLOCK) void sgns_dot_kernel(
    const int* __restrict__ vii32,  // raw words of the index array
    const float* __restrict__ W,
    float* __restrict__ out) {
    const int tid  = threadIdx.x;
    const int lane = tid & (LPS - 1);
    const int s    = blockIdx.x * SPB + (tid >> 4);

    // Index-width detection: int64 indices (< 2^20) have all-zero odd
    // int32 words. Check 4 of them -> false-positive prob ~1e-24.
    // Wave-uniform condition => scalar branch, no divergence, and we never
    // touch bytes beyond the actual buffer in either case.
    const bool idx64 = ((vii32[1] | vii32[3] | vii32[5] | vii32[7]) == 0);
    int i0, i1;
    if (idx64) { i0 = vii32[4 * s];     i1 = vii32[4 * s + 2]; }
    else       { i0 = vii32[2 * s];     i1 = vii32[2 * s + 1]; }

    const float4* rowA = (const float4*)(W + (size_t)i0 * NB_DIMS);
    const float4* rowB = (const float4*)(W + (size_t)i1 * NB_DIMS);

    // 4 independent 16B loads issued back-to-back (good MLP).
    const float4 a0 = rowA[lane];
    const float4 a1 = rowA[lane + LPS];
    const float4 b0 = rowB[lane];
    const float4 b1 = rowB[lane + LPS];

    float acc = 0.0f;
    acc = fmaf(a0.x, b0.x, acc);
    acc = fmaf(a0.y, b0.y, acc);
    acc = fmaf(a0.z, b0.z, acc);
    acc = fmaf(a0.w, b0.w, acc);
    acc = fmaf(a1.x, b1.x, acc);
    acc = fmaf(a1.y, b1.y, acc);
    acc = fmaf(a1.z, b1.z, acc);
    acc = fmaf(a1.w, b1.w, acc);

    // Butterfly reduce across the 16-lane group (groups are 16-aligned,
    // so xor offsets < 16 stay inside the group).
#pragma unroll
    for (int off = 8; off >= 1; off >>= 1)
        acc += __shfl_xor(acc, off, 64);

    if (lane == 0) out[s] = acc;
}

extern "C" void kernel_launch(void* const* d_in, const int* in_sizes, int n_in,
                              void* d_out, int out_size, void* d_ws, size_t ws_size,
                              hipStream_t stream) {
    const int* vii = (const int*)d_in[0];
    const float* W = (const float*)d_in[1];
    float* out = (float*)d_out;

    dim3 grid(BATCH / SPB);   // 1024 blocks
    dim3 block(BLOCK);        // 256 threads = 16 samples/block
    sgns_dot_kernel<<<grid, block, 0, stream>>>(vii, W, out);
}